// Round 5
// baseline (221.989 us; speedup 1.0000x reference)
//
#include <hip/hip_runtime.h>
#include <hip/hip_bf16.h>
#include <math.h>

#define BB 4
#define CC 64
#define DD 8
#define NN 4096

typedef __attribute__((ext_vector_type(4))) short short4v;  // 4 bf16 = 2 VGPRs
typedef __attribute__((ext_vector_type(4))) float f32x4;

// Target builtins only exist in the DEVICE pass. The host pass still
// semantic-checks __global__ bodies, so its stub must be __device__ __host__.
#if defined(__HIP_DEVICE_COMPILE__)
  #if __has_builtin(__builtin_amdgcn_mfma_f32_16x16x16bf16_1k)
    #define MFMA16(A, B, C) __builtin_amdgcn_mfma_f32_16x16x16bf16_1k(A, B, C, 0, 0, 0)
  #elif __has_builtin(__builtin_amdgcn_mfma_f32_16x16x16_bf16)
    #define MFMA16(A, B, C) __builtin_amdgcn_mfma_f32_16x16x16_bf16(A, B, C, 0, 0, 0)
  #else
    #error "no 16x16x16 bf16 MFMA builtin in device pass"
  #endif
#else
  static __device__ __host__ inline f32x4 MFMA16(short4v, short4v, f32x4 c) { return c; }
#endif

// ---------------------------------------------------------------------------
// Kernel 1: q/k/v projections -> bf16. Re-gridded for occupancy:
// grid (B*16, 18): y<16 -> 4 v-channels [4y,4y+4); y==16 -> q; y==17 -> k.
// q,k stored [B][N][8] bf16; v stored transposed [B][C][N] bf16.
// ---------------------------------------------------------------------------
__global__ __launch_bounds__(256) void qkv_kernel(
    const float* __restrict__ x,  const float* __restrict__ Wq, const float* __restrict__ bq,
    const float* __restrict__ Wk, const float* __restrict__ bk,
    const float* __restrict__ Wv, const float* __restrict__ bv,
    __hip_bfloat16* __restrict__ qb, __hip_bfloat16* __restrict__ kb,
    __hip_bfloat16* __restrict__ vT)
{
#pragma clang fp contract(fast)
    int bx = blockIdx.x;             // B*16
    int z  = blockIdx.y;             // 0..17
    int b = bx >> 4;
    int n = (bx & 15) * 256 + threadIdx.x;

    const float* xb = x + (size_t)b * CC * NN + n;
    float xr[CC];
    #pragma unroll
    for (int c = 0; c < CC; ++c) xr[c] = xb[(size_t)c * NN];   // coalesced

    if (z < 16) {
        int e0 = z * 4;
        #pragma unroll
        for (int e = 0; e < 4; ++e) {
            float a = bv[e0 + e];
            #pragma unroll
            for (int c = 0; c < CC; ++c)
                a = fmaf(Wv[(e0 + e) * CC + c], xr[c], a);
            vT[((size_t)b * CC + e0 + e) * NN + n] = __float2bfloat16(a);
        }
    } else {
        const float* W = (z == 16) ? Wq : Wk;
        const float* bb = (z == 16) ? bq : bk;
        __hip_bfloat16* o = (z == 16) ? qb : kb;
        __hip_bfloat16 t[DD];
        #pragma unroll
        for (int d = 0; d < DD; ++d) {
            float a = bb[d];
            #pragma unroll
            for (int c = 0; c < CC; ++c)
                a = fmaf(W[d * CC + c], xr[c], a);
            t[d] = __float2bfloat16(a);
        }
        *(uint4*)(o + ((size_t)b * NN + n) * DD) = *(uint4*)t;  // 16B coalesced
    }
}

// ---------------------------------------------------------------------------
// Kernel 2: MFMA flash partials, all in-register (no LDS, no barriers).
// Per 16-key subchunk:  S^T = mfma16(A=k_frag, B=q_frag)  ->  S^T C/D layout
// (col=query=lane&15, rows=key=quad*4+r) IS the PV A-operand layout
// (A[m=query=lane&15][k=key=quad*4+j]).  exp + pack in-register, then
// 4x PV mfma16 with V B-frags (4 consecutive keys, fixed channel) = 8B loads
// from channel-major vT.  Reduction dim D=8 < K=16: quads 2,3 zeroed.
// Grid: B * 64 qtiles * KS; wave owns 16 queries.
// ---------------------------------------------------------------------------
__global__ __launch_bounds__(256) void flash_kernel(
    const __hip_bfloat16* __restrict__ qb, const __hip_bfloat16* __restrict__ kb,
    const __hip_bfloat16* __restrict__ vT, float* __restrict__ accbuf,
    float* __restrict__ sbuf, int KS, int kps)
{
    int tid = threadIdx.x;
    int wave = tid >> 6, lane = tid & 63;
    int quad = lane >> 4, l16 = lane & 15;

    int blk = blockIdx.x;
    int split = blk % KS;
    int t2 = blk / KS;
    int qtile = t2 & 63;
    int b = t2 >> 6;
    int n0 = qtile * 64 + wave * 16;

    const short4v z4s = {0, 0, 0, 0};
    // Q B-frag: B[k=d=quad*4+j][n=query=l16]; d>=8 zero
    short4v qf = z4s;
    if (quad < 2)
        qf = *(const short4v*)(qb + ((size_t)b * NN + n0 + l16) * DD + quad * 4);

    f32x4 o[4];
    #pragma unroll
    for (int t = 0; t < 4; ++t) o[t] = (f32x4){0.f, 0.f, 0.f, 0.f};
    float ssum = 0.f;

    const __hip_bfloat16* kbb = kb + (size_t)b * NN * DD;
    const __hip_bfloat16* vbb = vT + (size_t)b * CC * NN;
    int m0 = split * kps;

    for (int ch = 0; ch < kps; ch += 32) {
        #pragma unroll
        for (int h = 0; h < 2; ++h) {
            int mb = m0 + ch + h * 16;
            // K A-frag: A[m=key=l16][k=d=quad*4+j]; d>=8 zero
            short4v kf = z4s;
            if (quad < 2)
                kf = *(const short4v*)(kbb + ((size_t)(mb + l16)) * DD + quad * 4);
            // V B-frags: B[k=key=quad*4+j][n=ch=t*16+l16]
            short4v vf0 = *(const short4v*)(vbb + ((size_t)(0 * 16 + l16)) * NN + mb + quad * 4);
            short4v vf1 = *(const short4v*)(vbb + ((size_t)(1 * 16 + l16)) * NN + mb + quad * 4);
            short4v vf2 = *(const short4v*)(vbb + ((size_t)(2 * 16 + l16)) * NN + mb + quad * 4);
            short4v vf3 = *(const short4v*)(vbb + ((size_t)(3 * 16 + l16)) * NN + mb + quad * 4);

            f32x4 st = MFMA16(kf, qf, ((f32x4){0.f, 0.f, 0.f, 0.f}));
            float w0 = __expf(st[0]), w1 = __expf(st[1]);
            float w2 = __expf(st[2]), w3 = __expf(st[3]);
            ssum += (w0 + w1) + (w2 + w3);

            union { short4v s; __hip_bfloat162 h2[2]; } pu;
            pu.h2[0] = __float22bfloat162_rn(make_float2(w0, w1));
            pu.h2[1] = __float22bfloat162_rn(make_float2(w2, w3));

            o[0] = MFMA16(pu.s, vf0, o[0]);
            o[1] = MFMA16(pu.s, vf1, o[1]);
            o[2] = MFMA16(pu.s, vf2, o[2]);
            o[3] = MFMA16(pu.s, vf3, o[3]);
        }
    }

    // O: D[row=query=quad*4+r][col=ch=t*16+l16]
    float* ab = accbuf + (((size_t)(b * KS + split)) * NN + n0) * CC;
    #pragma unroll
    for (int t = 0; t < 4; ++t)
        #pragma unroll
        for (int r = 0; r < 4; ++r)
            ab[(quad * 4 + r) * CC + t * 16 + l16] = o[t][r];

    // row sums: lane holds query l16 partial (this quad's keys); reduce quads
    ssum += __shfl_xor(ssum, 16);
    ssum += __shfl_xor(ssum, 32);
    if (lane < 16)
        sbuf[(size_t)(b * KS + split) * NN + n0 + lane] = ssum;
}

// ---------------------------------------------------------------------------
// Kernel 3: reduce splits, normalize, gamma*o + x. 16-position tiles for
// occupancy (B*256 blocks); LDS transpose keeps the 8x-bigger acc reads
// 256B-coalesced, out writes in 64B segments.
// ---------------------------------------------------------------------------
__global__ __launch_bounds__(256) void merge_kernel(
    const float* __restrict__ accbuf, const float* __restrict__ sbuf,
    const float* __restrict__ x, const float* __restrict__ gamma,
    float* __restrict__ out, int KS)
{
    __shared__ float tile[16 * 65];
    __shared__ float stl[16];
    int blk = blockIdx.x;            // B * 256
    int b = blk >> 8;
    int n0 = (blk & 255) * 16;
    int tid = threadIdx.x;

    if (tid < 16) {
        float st = 0.f;
        for (int sp = 0; sp < KS; ++sp)
            st += sbuf[(size_t)(b * KS + sp) * NN + n0 + tid];
        stl[tid] = 1.0f / st;
    }
    #pragma unroll
    for (int p = 0; p < 4; ++p) {
        int e = p * 256 + tid;
        int c = e & 63, nl = e >> 6;
        float a = 0.f;
        for (int sp = 0; sp < KS; ++sp)
            a += accbuf[(((size_t)(b * KS + sp) * NN) + n0 + nl) * CC + c];
        tile[nl * 65 + c] = a;
    }
    __syncthreads();
    float g = gamma[0];
    #pragma unroll
    for (int p = 0; p < 4; ++p) {
        int e = p * 256 + tid;
        int nl = e & 15, c = e >> 4;
        size_t xi = ((size_t)b * CC + c) * NN + n0 + nl;
        out[xi] = g * tile[nl * 65 + c] * stl[nl] + x[xi];
    }
}

// ---------------------------------------------------------------------------
extern "C" void kernel_launch(void* const* d_in, const int* in_sizes, int n_in,
                              void* d_out, int out_size, void* d_ws, size_t ws_size,
                              hipStream_t stream)
{
    const float* x     = (const float*)d_in[0];
    const float* Wq    = (const float*)d_in[1];
    const float* bq    = (const float*)d_in[2];
    const float* Wk    = (const float*)d_in[3];
    const float* bk    = (const float*)d_in[4];
    const float* Wv    = (const float*)d_in[5];
    const float* bv    = (const float*)d_in[6];
    const float* gamma = (const float*)d_in[7];
    float* out = (float*)d_out;

    float* ws = (float*)d_ws;
    size_t off = 0;
    __hip_bfloat16* qb = (__hip_bfloat16*)(ws + off); off += (size_t)BB * NN * DD / 2;
    __hip_bfloat16* kb = (__hip_bfloat16*)(ws + off); off += (size_t)BB * NN * DD / 2 + 64;  // +pad
    __hip_bfloat16* vT = (__hip_bfloat16*)(ws + off); off += (size_t)BB * CC * NN / 2 + 64;  // +pad

    long long avail = (long long)(ws_size / 4) - (long long)off;
    const long long per_split = (long long)BB * NN * CC + (long long)BB * NN;
    int KS = 8;
    while (KS > 1 && per_split * KS > avail) KS >>= 1;

    float* accbuf = ws + off; off += (size_t)BB * KS * NN * CC;
    float* sbuf   = ws + off; off += (size_t)BB * KS * NN;

    qkv_kernel<<<dim3(BB * 16, 18), 256, 0, stream>>>(x, Wq, bq, Wk, bk, Wv, bv, qb, kb, vT);
    flash_kernel<<<BB * 64 * KS, 256, 0, stream>>>(qb, kb, vT, accbuf, sbuf, KS, NN / KS);
    merge_kernel<<<BB * 256, 256, 0, stream>>>(accbuf, sbuf, x, gamma, out, KS);
}

// Round 6
// 159.616 us; speedup vs baseline: 1.3908x; 1.3908x over previous
//
#include <hip/hip_runtime.h>
#include <hip/hip_bf16.h>
#include <math.h>

#define BB 4
#define CC 64
#define DD 8
#define NN 4096
#define LOG2E 1.44269504088896340736f

typedef __attribute__((ext_vector_type(4))) short short4v;   // 4 bf16 = 2 VGPRs
typedef __attribute__((ext_vector_type(16))) float f32x16;

// Device-pass-only builtins; host pass still semantic-checks __global__ bodies.
#if defined(__HIP_DEVICE_COMPILE__)
  #if __has_builtin(__builtin_amdgcn_mfma_f32_32x32x8bf16_1k)
    #define MFMA32x8(A, B, C) __builtin_amdgcn_mfma_f32_32x32x8bf16_1k(A, B, C, 0, 0, 0)
  #elif __has_builtin(__builtin_amdgcn_mfma_f32_32x32x8_bf16)
    #define MFMA32x8(A, B, C) __builtin_amdgcn_mfma_f32_32x32x8_bf16(A, B, C, 0, 0, 0)
  #else
    #error "no 32x32x8 bf16 MFMA builtin in device pass"
  #endif
#else
  static __device__ __host__ inline f32x16 MFMA32x8(short4v, short4v, f32x16 c) { return c; }
#endif

// ---------------------------------------------------------------------------
// Kernel 1: q/k/v projections -> bf16.
// grid (B*16, 10): z<8 -> 8 v-channels [8z,8z+8); z==8 -> q (scaled by
// log2(e) so flash can use exp2 = raw v_exp_f32); z==9 -> k.
// q,k stored [B][N][8] bf16; v stored transposed [B][C][N] bf16.
// ---------------------------------------------------------------------------
__global__ __launch_bounds__(256) void qkv_kernel(
    const float* __restrict__ x,  const float* __restrict__ Wq, const float* __restrict__ bq,
    const float* __restrict__ Wk, const float* __restrict__ bk,
    const float* __restrict__ Wv, const float* __restrict__ bv,
    __hip_bfloat16* __restrict__ qb, __hip_bfloat16* __restrict__ kb,
    __hip_bfloat16* __restrict__ vT)
{
#pragma clang fp contract(fast)
    int bx = blockIdx.x;             // B*16
    int z  = blockIdx.y;             // 0..9
    int b = bx >> 4;
    int n = (bx & 15) * 256 + threadIdx.x;

    const float* xb = x + (size_t)b * CC * NN + n;
    float xr[CC];
    #pragma unroll
    for (int c = 0; c < CC; ++c) xr[c] = xb[(size_t)c * NN];   // coalesced

    if (z < 8) {
        int e0 = z * 8;
        #pragma unroll
        for (int e = 0; e < 8; ++e) {
            float a = bv[e0 + e];
            #pragma unroll
            for (int c = 0; c < CC; ++c)
                a = fmaf(Wv[(e0 + e) * CC + c], xr[c], a);
            vT[((size_t)b * CC + e0 + e) * NN + n] = __float2bfloat16(a);
        }
    } else {
        bool isq = (z == 8);
        const float* W  = isq ? Wq : Wk;
        const float* bb = isq ? bq : bk;
        __hip_bfloat16* o = isq ? qb : kb;
        float scale = isq ? LOG2E : 1.0f;
        __hip_bfloat16 t[DD];
        #pragma unroll
        for (int d = 0; d < DD; ++d) {
            float a = bb[d];
            #pragma unroll
            for (int c = 0; c < CC; ++c)
                a = fmaf(W[d * CC + c], xr[c], a);
            t[d] = __float2bfloat16(a * scale);
        }
        *(uint4*)(o + ((size_t)b * NN + n) * DD) = *(uint4*)t;  // 16B coalesced
    }
}

// ---------------------------------------------------------------------------
// Kernel 2: MFMA flash partials with 32x32x8 (K=8 == D: zero waste).
// Wave owns 32 queries x 64 channels. Per 32-key iter:
//   S^T = mfma_32x32x8(A=K, B=Q): lane(l32,h2) reg r = S[q=l32][key=(r&3)+8(r>>2)+4h2]
//   exp2 in-register; regs 4g..4g+3 = PV A-frag for keys 8g..8g+7 (j=(r&3)).
//   8 PV mfma into two 32-channel accumulators. k/v register-prefetched one
//   iteration ahead. b = blk&3 -> per-XCD batch locality (vT L2-resident).
// Grid: BB * (N/128) * KS, 256 thr (4 waves = 4 query tiles).
// ---------------------------------------------------------------------------
#define LDK(M)      (*(const short4v*)(kbb + (size_t)((M) + l32) * DD + h2 * 4))
#define VLD(G,T,M)  (*(const short4v*)(vbb + (size_t)((T) * 32 + l32) * NN + (M) + (G) * 8 + h2 * 4))

__global__ __launch_bounds__(256, 4) void flash_kernel(
    const __hip_bfloat16* __restrict__ qb, const __hip_bfloat16* __restrict__ kb,
    const __hip_bfloat16* __restrict__ vT, float* __restrict__ accbuf,
    float* __restrict__ sbuf, int KS, int kslog, int kps)
{
    int tid = threadIdx.x;
    int wave = tid >> 6, lane = tid & 63;
    int l32 = lane & 31, h2 = lane >> 5;

    int blk = blockIdx.x;            // ((qchunk*KS)+split)*4 + b
    int b = blk & (BB - 1);
    int rest = blk >> 2;
    int split = rest & (KS - 1);
    int qchunk = rest >> kslog;
    int n0 = qchunk * 128 + wave * 32;

    // Q B-frag: B[k=d=4h2+j][n=query=l32]
    short4v qf = *(const short4v*)(qb + ((size_t)b * NN + n0 + l32) * DD + h2 * 4);

    const __hip_bfloat16* kbb = kb + (size_t)b * NN * DD;
    const __hip_bfloat16* vbb = vT + (size_t)b * CC * NN;
    int m0 = split * kps;
    int niter = kps >> 5;

    f32x16 zzv, o0, o1;
    #pragma unroll
    for (int r = 0; r < 16; ++r) { zzv[r] = 0.f; o0[r] = 0.f; o1[r] = 0.f; }
    float ssum = 0.f;

    // prefetch iteration 0
    short4v kc  = LDK(m0);
    short4v c00 = VLD(0, 0, m0), c01 = VLD(0, 1, m0);
    short4v c10 = VLD(1, 0, m0), c11 = VLD(1, 1, m0);
    short4v c20 = VLD(2, 0, m0), c21 = VLD(2, 1, m0);
    short4v c30 = VLD(3, 0, m0), c31 = VLD(3, 1, m0);

    for (int it = 0; it < niter; ++it) {
        int mn = m0 + (it + 1) * 32;   // last-iter prefetch overruns into pad
        short4v kN  = LDK(mn);
        short4v n00 = VLD(0, 0, mn), n01 = VLD(0, 1, mn);
        short4v n10 = VLD(1, 0, mn), n11 = VLD(1, 1, mn);
        short4v n20 = VLD(2, 0, mn), n21 = VLD(2, 1, mn);
        short4v n30 = VLD(3, 0, mn), n31 = VLD(3, 1, mn);

        f32x16 st = MFMA32x8(kc, qf, zzv);
        float w[16];
        #pragma unroll
        for (int r = 0; r < 16; ++r) w[r] = exp2f(st[r]);
        ssum += (((w[0] + w[1]) + (w[2] + w[3])) + ((w[4] + w[5]) + (w[6] + w[7])))
              + (((w[8] + w[9]) + (w[10] + w[11])) + ((w[12] + w[13]) + (w[14] + w[15])));

        union { short4v s; __hip_bfloat162 h[2]; } u0, u1, u2, u3;
        u0.h[0] = __float22bfloat162_rn(make_float2(w[0],  w[1]));
        u0.h[1] = __float22bfloat162_rn(make_float2(w[2],  w[3]));
        u1.h[0] = __float22bfloat162_rn(make_float2(w[4],  w[5]));
        u1.h[1] = __float22bfloat162_rn(make_float2(w[6],  w[7]));
        u2.h[0] = __float22bfloat162_rn(make_float2(w[8],  w[9]));
        u2.h[1] = __float22bfloat162_rn(make_float2(w[10], w[11]));
        u3.h[0] = __float22bfloat162_rn(make_float2(w[12], w[13]));
        u3.h[1] = __float22bfloat162_rn(make_float2(w[14], w[15]));

        o0 = MFMA32x8(u0.s, c00, o0);  o1 = MFMA32x8(u0.s, c01, o1);
        o0 = MFMA32x8(u1.s, c10, o0);  o1 = MFMA32x8(u1.s, c11, o1);
        o0 = MFMA32x8(u2.s, c20, o0);  o1 = MFMA32x8(u2.s, c21, o1);
        o0 = MFMA32x8(u3.s, c30, o0);  o1 = MFMA32x8(u3.s, c31, o1);

        kc = kN;
        c00 = n00; c01 = n01; c10 = n10; c11 = n11;
        c20 = n20; c21 = n21; c30 = n30; c31 = n31;
    }

    // O: D[row=query=(r&3)+8(r>>2)+4h2][col=channel], two 32-channel halves
    float* ab = accbuf + (((size_t)(b * KS + split)) * NN + n0) * CC + l32;
    #pragma unroll
    for (int r = 0; r < 16; ++r) {
        int qrow = (r & 3) + 8 * (r >> 2) + 4 * h2;
        ab[(size_t)qrow * CC]      = o0[r];
        ab[(size_t)qrow * CC + 32] = o1[r];
    }
    ssum += __shfl_xor(ssum, 32);     // combine key-halves -> full 32-key sum
    if (lane < 32)
        sbuf[(size_t)(b * KS + split) * NN + n0 + l32] = ssum;
}

// ---------------------------------------------------------------------------
// Kernel 3: reduce splits, normalize, gamma*o + x. Grid: B*256 blocks.
// ---------------------------------------------------------------------------
__global__ __launch_bounds__(256) void merge_kernel(
    const float* __restrict__ accbuf, const float* __restrict__ sbuf,
    const float* __restrict__ x, const float* __restrict__ gamma,
    float* __restrict__ out, int KS)
{
    __shared__ float tile[16 * 65];
    __shared__ float stl[16];
    int blk = blockIdx.x;            // B * 256
    int b = blk >> 8;
    int n0 = (blk & 255) * 16;
    int tid = threadIdx.x;

    if (tid < 16) {
        float st = 0.f;
        for (int sp = 0; sp < KS; ++sp)
            st += sbuf[(size_t)(b * KS + sp) * NN + n0 + tid];
        stl[tid] = 1.0f / st;
    }
    #pragma unroll
    for (int p = 0; p < 4; ++p) {
        int e = p * 256 + tid;
        int c = e & 63, nl = e >> 6;
        float a = 0.f;
        for (int sp = 0; sp < KS; ++sp)
            a += accbuf[(((size_t)(b * KS + sp) * NN) + n0 + nl) * CC + c];
        tile[nl * 65 + c] = a;
    }
    __syncthreads();
    float g = gamma[0];
    #pragma unroll
    for (int p = 0; p < 4; ++p) {
        int e = p * 256 + tid;
        int nl = e & 15, c = e >> 4;
        size_t xi = ((size_t)b * CC + c) * NN + n0 + nl;
        out[xi] = g * tile[nl * 65 + c] * stl[nl] + x[xi];
    }
}

// ---------------------------------------------------------------------------
extern "C" void kernel_launch(void* const* d_in, const int* in_sizes, int n_in,
                              void* d_out, int out_size, void* d_ws, size_t ws_size,
                              hipStream_t stream)
{
    const float* x     = (const float*)d_in[0];
    const float* Wq    = (const float*)d_in[1];
    const float* bq    = (const float*)d_in[2];
    const float* Wk    = (const float*)d_in[3];
    const float* bk    = (const float*)d_in[4];
    const float* Wv    = (const float*)d_in[5];
    const float* bv    = (const float*)d_in[6];
    const float* gamma = (const float*)d_in[7];
    float* out = (float*)d_out;

    float* ws = (float*)d_ws;
    size_t off = 0;
    __hip_bfloat16* qb = (__hip_bfloat16*)(ws + off); off += (size_t)BB * NN * DD / 2 + 256;
    __hip_bfloat16* kb = (__hip_bfloat16*)(ws + off); off += (size_t)BB * NN * DD / 2 + 256;  // prefetch pad
    __hip_bfloat16* vT = (__hip_bfloat16*)(ws + off); off += (size_t)BB * CC * NN / 2 + 256;  // prefetch pad

    long long avail = (long long)(ws_size / 4) - (long long)off;
    const long long per_split = (long long)BB * NN * CC + (long long)BB * NN;
    int KS = 8;
    while (KS > 1 && per_split * KS > avail) KS >>= 1;
    int kslog = 0;
    while ((1 << kslog) < KS) ++kslog;

    float* accbuf = ws + off; off += (size_t)BB * KS * NN * CC;
    float* sbuf   = ws + off; off += (size_t)BB * KS * NN;

    qkv_kernel<<<dim3(BB * 16, 10), 256, 0, stream>>>(x, Wq, bq, Wk, bk, Wv, bv, qb, kb, vT);
    flash_kernel<<<BB * (NN / 128) * KS, 256, 0, stream>>>(qb, kb, vT, accbuf, sbuf,
                                                           KS, kslog, NN / KS);
    merge_kernel<<<BB * 256, 256, 0, stream>>>(accbuf, sbuf, x, gamma, out, KS);
}